// Round 2
// baseline (664.743 us; speedup 1.0000x reference)
//
#include <hip/hip_runtime.h>

#define IN_F 256
#define OUT_F 64
#define SCAN_T 1024

// ---------------------------------------------------------------- histogram
__global__ __launch_bounds__(256) void hist_kernel(const int* __restrict__ dst,
                                                   int* __restrict__ deg, int E) {
    int e = blockIdx.x * 256 + threadIdx.x;
    if (e < E) atomicAdd(&deg[dst[e]], 1);
}

// ---------------------------------------------------------------- scan (single block)
// In: cursor[] holds deg. Out: off[0..N] exclusive offsets, cursor[] = off copy.
__global__ __launch_bounds__(SCAN_T) void scan_kernel(int* __restrict__ cursor,
                                                      int* __restrict__ off, int N) {
    __shared__ int s[SCAN_T];
    const int t = threadIdx.x;
    const int chunk = (N + SCAN_T - 1) / SCAN_T;
    const int b = t * chunk;
    const int e = min(b + chunk, N);

    int mysum = 0;
    for (int i = b; i < e; ++i) mysum += cursor[i];
    s[t] = mysum;
    __syncthreads();
    // Hillis-Steele inclusive scan
    for (int o = 1; o < SCAN_T; o <<= 1) {
        int v = (t >= o) ? s[t - o] : 0;
        __syncthreads();
        s[t] += v;
        __syncthreads();
    }
    int running = s[t] - mysum; // exclusive prefix for this chunk
    for (int i = b; i < e; ++i) {
        int d = cursor[i];
        off[i] = running;
        cursor[i] = running;
        running += d;
    }
    if (t == 0) off[N] = s[SCAN_T - 1];
}

// ---------------------------------------------------------------- edge sort (scatter payloads)
__global__ __launch_bounds__(256) void sort_kernel(const int* __restrict__ src,
                                                   const int* __restrict__ dst,
                                                   const float* __restrict__ ew,
                                                   int* __restrict__ cursor,
                                                   int2* __restrict__ payload, int E) {
    int e = blockIdx.x * 256 + threadIdx.x;
    if (e < E) {
        int d = dst[e];
        int p = atomicAdd(&cursor[d], 1);
        int2 pl;
        pl.x = src[e];
        pl.y = __float_as_int(ew[e]);
        payload[p] = pl;
    }
}

// ---------------------------------------------------------------- GEMM h = feat @ W
__global__ __launch_bounds__(256) void gemm_kernel(const float* __restrict__ feat,
                                                   const float* __restrict__ W,
                                                   float* __restrict__ h, int N) {
    const int tid = threadIdx.x;
    const int cg = tid & 15;   // column group: cols 4*cg .. 4*cg+3
    const int rg = tid >> 4;   // row group
    const int row0 = blockIdx.x * 64 + rg * 4;

    const float4* __restrict__ feat4 = (const float4*)feat; // [N][64]
    const float4* __restrict__ W4 = (const float4*)W;       // [256][16]

    const int r0 = min(row0 + 0, N - 1);
    const int r1 = min(row0 + 1, N - 1);
    const int r2 = min(row0 + 2, N - 1);
    const int r3 = min(row0 + 3, N - 1);

    float4 acc0 = {0.f, 0.f, 0.f, 0.f};
    float4 acc1 = {0.f, 0.f, 0.f, 0.f};
    float4 acc2 = {0.f, 0.f, 0.f, 0.f};
    float4 acc3 = {0.f, 0.f, 0.f, 0.f};

#define FMA4(ACC, A, B)                                                        \
    ACC.x = fmaf(A, B.x, ACC.x);                                               \
    ACC.y = fmaf(A, B.y, ACC.y);                                               \
    ACC.z = fmaf(A, B.z, ACC.z);                                               \
    ACC.w = fmaf(A, B.w, ACC.w);

#pragma unroll 4
    for (int k = 0; k < IN_F; k += 4) {
        const int k4 = k >> 2;
        float4 a0 = feat4[r0 * (IN_F / 4) + k4];
        float4 a1 = feat4[r1 * (IN_F / 4) + k4];
        float4 a2 = feat4[r2 * (IN_F / 4) + k4];
        float4 a3 = feat4[r3 * (IN_F / 4) + k4];
        float4 b0 = W4[(k + 0) * (OUT_F / 4) + cg];
        float4 b1 = W4[(k + 1) * (OUT_F / 4) + cg];
        float4 b2 = W4[(k + 2) * (OUT_F / 4) + cg];
        float4 b3 = W4[(k + 3) * (OUT_F / 4) + cg];

        FMA4(acc0, a0.x, b0); FMA4(acc0, a0.y, b1); FMA4(acc0, a0.z, b2); FMA4(acc0, a0.w, b3);
        FMA4(acc1, a1.x, b0); FMA4(acc1, a1.y, b1); FMA4(acc1, a1.z, b2); FMA4(acc1, a1.w, b3);
        FMA4(acc2, a2.x, b0); FMA4(acc2, a2.y, b1); FMA4(acc2, a2.z, b2); FMA4(acc2, a2.w, b3);
        FMA4(acc3, a3.x, b0); FMA4(acc3, a3.y, b1); FMA4(acc3, a3.z, b2); FMA4(acc3, a3.w, b3);
    }
#undef FMA4

    float4* __restrict__ h4 = (float4*)h; // [N][16]
    if (row0 + 0 < N) h4[(row0 + 0) * (OUT_F / 4) + cg] = acc0;
    if (row0 + 1 < N) h4[(row0 + 1) * (OUT_F / 4) + cg] = acc1;
    if (row0 + 2 < N) h4[(row0 + 2) * (OUT_F / 4) + cg] = acc2;
    if (row0 + 3 < N) h4[(row0 + 3) * (OUT_F / 4) + cg] = acc3;
}

// ---------------------------------------------------------------- gather + ReLU
// One wave per node; lane = output column. Register accumulation, no atomics.
__global__ __launch_bounds__(256) void gather_kernel(const float* __restrict__ h,
                                                     const int2* __restrict__ payload,
                                                     const int* __restrict__ off,
                                                     float* __restrict__ out, int N) {
    const int v = blockIdx.x * 4 + (threadIdx.x >> 6);
    const int lane = threadIdx.x & 63;
    if (v >= N) return;
    const int b = off[v];
    const int e = off[v + 1];
    float acc = 0.f;
    for (int i = b; i < e; ++i) {
        int2 pl = payload[i];            // broadcast across the wave
        float w = __int_as_float(pl.y);
        acc = fmaf(h[pl.x * OUT_F + lane], w, acc);
    }
    out[v * OUT_F + lane] = fmaxf(acc, 0.f);
}

// ---------------------------------------------------------------- launch
extern "C" void kernel_launch(void* const* d_in, const int* in_sizes, int n_in,
                              void* d_out, int out_size, void* d_ws, size_t ws_size,
                              hipStream_t stream) {
    const float* feat = (const float*)d_in[0];
    const float* W    = (const float*)d_in[1];
    const float* ew   = (const float*)d_in[2];
    const int*   src  = (const int*)d_in[3];
    const int*   dst  = (const int*)d_in[4];
    float* out = (float*)d_out;

    const int N = in_sizes[0] / IN_F;
    const int E = in_sizes[2];

    // workspace layout (all 4-byte types)
    char* ws = (char*)d_ws;
    float* h       = (float*)ws;                  ws += (size_t)N * OUT_F * 4;  // 25.6 MB
    int*   cursor  = (int*)ws;                    ws += (size_t)N * 4;          //  0.4 MB
    int*   off     = (int*)ws;                    ws += (size_t)(N + 1) * 4;    //  0.4 MB
    int2*  payload = (int2*)ws;                                                  // 12.8 MB

    hipMemsetAsync(cursor, 0, (size_t)N * 4, stream);

    const int eblocks = (E + 255) / 256;
    hipLaunchKernelGGL(hist_kernel, dim3(eblocks), dim3(256), 0, stream, dst, cursor, E);
    hipLaunchKernelGGL(scan_kernel, dim3(1), dim3(SCAN_T), 0, stream, cursor, off, N);
    hipLaunchKernelGGL(sort_kernel, dim3(eblocks), dim3(256), 0, stream, src, dst, ew, cursor, payload, E);
    hipLaunchKernelGGL(gemm_kernel, dim3((N + 63) / 64), dim3(256), 0, stream, feat, W, h, N);
    hipLaunchKernelGGL(gather_kernel, dim3((N + 3) / 4), dim3(256), 0, stream, h, payload, off, out, N);
}

// Round 3
// 446.437 us; speedup vs baseline: 1.4890x; 1.4890x over previous
//
#include <hip/hip_runtime.h>

#define IN_F 256
#define OUT_F 64
#define SCAN_ELEMS 2048   // per block: 256 threads x 8

// ---------------------------------------------------------------- histogram
__global__ __launch_bounds__(256) void hist_kernel(const int* __restrict__ dst,
                                                   int* __restrict__ deg, int E) {
    int e = blockIdx.x * 256 + threadIdx.x;
    if (e < E) atomicAdd(&deg[dst[e]], 1);
}

// ---------------------------------------------------------------- scan phase A: block sums
__global__ __launch_bounds__(256) void scanA_kernel(const int* __restrict__ deg,
                                                    int* __restrict__ bsum, int N) {
    __shared__ int s[256];
    const int t = threadIdx.x;
    const int base = blockIdx.x * SCAN_ELEMS + t * 8;
    int sum = 0;
#pragma unroll
    for (int j = 0; j < 8; ++j) {
        int i = base + j;
        if (i < N) sum += deg[i];
    }
    s[t] = sum;
    __syncthreads();
    for (int o = 128; o > 0; o >>= 1) {
        if (t < o) s[t] += s[t + o];
        __syncthreads();
    }
    if (t == 0) bsum[blockIdx.x] = s[0];
}

// ---------------------------------------------------------------- scan phase B: scan block sums (NB <= 256)
__global__ __launch_bounds__(256) void scanB_kernel(int* __restrict__ bsum,
                                                    int* __restrict__ off, int NB, int N) {
    __shared__ int s[256];
    const int t = threadIdx.x;
    int v = (t < NB) ? bsum[t] : 0;
    s[t] = v;
    __syncthreads();
    for (int o = 1; o < 256; o <<= 1) {
        int x = (t >= o) ? s[t - o] : 0;
        __syncthreads();
        s[t] += x;
        __syncthreads();
    }
    if (t < NB) bsum[t] = s[t] - v; // exclusive block prefix
    if (t == 255) off[N] = s[255];  // total edge count
}

// ---------------------------------------------------------------- scan phase C: local scan + offsets
// Reads deg (aliased with cursor), writes off[] and cursor[] (each element is
// read by its own thread before being overwritten -> safe).
__global__ __launch_bounds__(256) void scanC_kernel(const int* __restrict__ bsum,
                                                    int* __restrict__ off,
                                                    int* __restrict__ cursor, int N) {
    __shared__ int s[256];
    const int t = threadIdx.x;
    const int base = blockIdx.x * SCAN_ELEMS + t * 8;
    int loc[8];
    int sum = 0;
#pragma unroll
    for (int j = 0; j < 8; ++j) {
        int i = base + j;
        loc[j] = (i < N) ? cursor[i] : 0;
        sum += loc[j];
    }
    s[t] = sum;
    __syncthreads();
    for (int o = 1; o < 256; o <<= 1) {
        int x = (t >= o) ? s[t - o] : 0;
        __syncthreads();
        s[t] += x;
        __syncthreads();
    }
    int run = bsum[blockIdx.x] + s[t] - sum; // exclusive prefix for this thread
#pragma unroll
    for (int j = 0; j < 8; ++j) {
        int i = base + j;
        if (i < N) {
            off[i] = run;
            cursor[i] = run;
            run += loc[j];
        }
    }
}

// ---------------------------------------------------------------- edge sort (scatter payloads)
__global__ __launch_bounds__(256) void sort_kernel(const int* __restrict__ src,
                                                   const int* __restrict__ dst,
                                                   const float* __restrict__ ew,
                                                   int* __restrict__ cursor,
                                                   int2* __restrict__ payload, int E) {
    int e = blockIdx.x * 256 + threadIdx.x;
    if (e < E) {
        int d = dst[e];
        int p = atomicAdd(&cursor[d], 1);
        int2 pl;
        pl.x = src[e];
        pl.y = __float_as_int(ew[e]);
        payload[p] = pl;
    }
}

// ---------------------------------------------------------------- GEMM h = feat @ W
__global__ __launch_bounds__(256) void gemm_kernel(const float* __restrict__ feat,
                                                   const float* __restrict__ W,
                                                   float* __restrict__ h, int N) {
    const int tid = threadIdx.x;
    const int cg = tid & 15;   // column group: cols 4*cg .. 4*cg+3
    const int rg = tid >> 4;   // row group
    const int row0 = blockIdx.x * 64 + rg * 4;

    const float4* __restrict__ feat4 = (const float4*)feat; // [N][64]
    const float4* __restrict__ W4 = (const float4*)W;       // [256][16]

    const int r0 = min(row0 + 0, N - 1);
    const int r1 = min(row0 + 1, N - 1);
    const int r2 = min(row0 + 2, N - 1);
    const int r3 = min(row0 + 3, N - 1);

    float4 acc0 = {0.f, 0.f, 0.f, 0.f};
    float4 acc1 = {0.f, 0.f, 0.f, 0.f};
    float4 acc2 = {0.f, 0.f, 0.f, 0.f};
    float4 acc3 = {0.f, 0.f, 0.f, 0.f};

#define FMA4(ACC, A, B)                                                        \
    ACC.x = fmaf(A, B.x, ACC.x);                                               \
    ACC.y = fmaf(A, B.y, ACC.y);                                               \
    ACC.z = fmaf(A, B.z, ACC.z);                                               \
    ACC.w = fmaf(A, B.w, ACC.w);

#pragma unroll 4
    for (int k = 0; k < IN_F; k += 4) {
        const int k4 = k >> 2;
        float4 a0 = feat4[r0 * (IN_F / 4) + k4];
        float4 a1 = feat4[r1 * (IN_F / 4) + k4];
        float4 a2 = feat4[r2 * (IN_F / 4) + k4];
        float4 a3 = feat4[r3 * (IN_F / 4) + k4];
        float4 b0 = W4[(k + 0) * (OUT_F / 4) + cg];
        float4 b1 = W4[(k + 1) * (OUT_F / 4) + cg];
        float4 b2 = W4[(k + 2) * (OUT_F / 4) + cg];
        float4 b3 = W4[(k + 3) * (OUT_F / 4) + cg];

        FMA4(acc0, a0.x, b0); FMA4(acc0, a0.y, b1); FMA4(acc0, a0.z, b2); FMA4(acc0, a0.w, b3);
        FMA4(acc1, a1.x, b0); FMA4(acc1, a1.y, b1); FMA4(acc1, a1.z, b2); FMA4(acc1, a1.w, b3);
        FMA4(acc2, a2.x, b0); FMA4(acc2, a2.y, b1); FMA4(acc2, a2.z, b2); FMA4(acc2, a2.w, b3);
        FMA4(acc3, a3.x, b0); FMA4(acc3, a3.y, b1); FMA4(acc3, a3.z, b2); FMA4(acc3, a3.w, b3);
    }
#undef FMA4

    float4* __restrict__ h4 = (float4*)h; // [N][16]
    if (row0 + 0 < N) h4[(row0 + 0) * (OUT_F / 4) + cg] = acc0;
    if (row0 + 1 < N) h4[(row0 + 1) * (OUT_F / 4) + cg] = acc1;
    if (row0 + 2 < N) h4[(row0 + 2) * (OUT_F / 4) + cg] = acc2;
    if (row0 + 3 < N) h4[(row0 + 3) * (OUT_F / 4) + cg] = acc3;
}

// ---------------------------------------------------------------- gather + ReLU
__global__ __launch_bounds__(256) void gather_kernel(const float* __restrict__ h,
                                                     const int2* __restrict__ payload,
                                                     const int* __restrict__ off,
                                                     float* __restrict__ out, int N) {
    const int v = blockIdx.x * 4 + (threadIdx.x >> 6);
    const int lane = threadIdx.x & 63;
    if (v >= N) return;
    const int b = off[v];
    const int e = off[v + 1];
    float acc = 0.f;
    for (int i = b; i < e; ++i) {
        int2 pl = payload[i]; // broadcast across the wave
        float w = __int_as_float(pl.y);
        acc = fmaf(h[pl.x * OUT_F + lane], w, acc);
    }
    out[v * OUT_F + lane] = fmaxf(acc, 0.f);
}

// ---------------------------------------------------------------- launch
extern "C" void kernel_launch(void* const* d_in, const int* in_sizes, int n_in,
                              void* d_out, int out_size, void* d_ws, size_t ws_size,
                              hipStream_t stream) {
    const float* feat = (const float*)d_in[0];
    const float* W    = (const float*)d_in[1];
    const float* ew   = (const float*)d_in[2];
    const int*   src  = (const int*)d_in[3];
    const int*   dst  = (const int*)d_in[4];
    float* out = (float*)d_out;

    const int N = in_sizes[0] / IN_F;
    const int E = in_sizes[2];

    // workspace layout (all 4-byte types)
    char* ws = (char*)d_ws;
    float* h       = (float*)ws;  ws += (size_t)N * OUT_F * 4;   // 25.6 MB
    int*   cursor  = (int*)ws;    ws += (size_t)N * 4;           //  0.4 MB (deg -> offsets)
    int*   off     = (int*)ws;    ws += (size_t)(N + 1) * 4;     //  0.4 MB
    int*   bsum    = (int*)ws;    ws += 256 * 4;                 //  1 KB
    int2*  payload = (int2*)ws;                                  // 12.8 MB

    hipMemsetAsync(cursor, 0, (size_t)N * 4, stream);

    const int eblocks = (E + 255) / 256;
    const int NB = (N + SCAN_ELEMS - 1) / SCAN_ELEMS; // 49 for N=100000

    hipLaunchKernelGGL(hist_kernel, dim3(eblocks), dim3(256), 0, stream, dst, cursor, E);
    hipLaunchKernelGGL(scanA_kernel, dim3(NB), dim3(256), 0, stream, cursor, bsum, N);
    hipLaunchKernelGGL(scanB_kernel, dim3(1), dim3(256), 0, stream, bsum, off, NB, N);
    hipLaunchKernelGGL(scanC_kernel, dim3(NB), dim3(256), 0, stream, bsum, off, cursor, N);
    hipLaunchKernelGGL(sort_kernel, dim3(eblocks), dim3(256), 0, stream, src, dst, ew, cursor, payload, E);
    hipLaunchKernelGGL(gemm_kernel, dim3((N + 63) / 64), dim3(256), 0, stream, feat, W, h, N);
    hipLaunchKernelGGL(gather_kernel, dim3((N + 3) / 4), dim3(256), 0, stream, h, payload, off, out, N);
}

// Round 4
// 357.203 us; speedup vs baseline: 1.8610x; 1.2498x over previous
//
#include <hip/hip_runtime.h>

#define IN_F 256
#define OUT_F 64
#define SCAN_ELEMS 2048   // per block: 256 threads x 8

typedef __bf16 bf16x8 __attribute__((ext_vector_type(8)));
typedef float f32x4 __attribute__((ext_vector_type(4)));

// ---------------------------------------------------------------- histogram
__global__ __launch_bounds__(256) void hist_kernel(const int* __restrict__ dst,
                                                   int* __restrict__ deg, int E) {
    int e = blockIdx.x * 256 + threadIdx.x;
    if (e < E) atomicAdd(&deg[dst[e]], 1);
}

// ---------------------------------------------------------------- scan phase A
__global__ __launch_bounds__(256) void scanA_kernel(const int* __restrict__ deg,
                                                    int* __restrict__ bsum, int N) {
    __shared__ int s[256];
    const int t = threadIdx.x;
    const int base = blockIdx.x * SCAN_ELEMS + t * 8;
    int sum = 0;
#pragma unroll
    for (int j = 0; j < 8; ++j) {
        int i = base + j;
        if (i < N) sum += deg[i];
    }
    s[t] = sum;
    __syncthreads();
    for (int o = 128; o > 0; o >>= 1) {
        if (t < o) s[t] += s[t + o];
        __syncthreads();
    }
    if (t == 0) bsum[blockIdx.x] = s[0];
}

// ---------------------------------------------------------------- scan phase B (NB <= 256)
__global__ __launch_bounds__(256) void scanB_kernel(int* __restrict__ bsum,
                                                    int* __restrict__ off, int NB, int N) {
    __shared__ int s[256];
    const int t = threadIdx.x;
    int v = (t < NB) ? bsum[t] : 0;
    s[t] = v;
    __syncthreads();
    for (int o = 1; o < 256; o <<= 1) {
        int x = (t >= o) ? s[t - o] : 0;
        __syncthreads();
        s[t] += x;
        __syncthreads();
    }
    if (t < NB) bsum[t] = s[t] - v; // exclusive block prefix
    if (t == 255) off[N] = s[255];
}

// ---------------------------------------------------------------- scan phase C
__global__ __launch_bounds__(256) void scanC_kernel(const int* __restrict__ bsum,
                                                    int* __restrict__ off,
                                                    int* __restrict__ cursor, int N) {
    __shared__ int s[256];
    const int t = threadIdx.x;
    const int base = blockIdx.x * SCAN_ELEMS + t * 8;
    int loc[8];
    int sum = 0;
#pragma unroll
    for (int j = 0; j < 8; ++j) {
        int i = base + j;
        loc[j] = (i < N) ? cursor[i] : 0;
        sum += loc[j];
    }
    s[t] = sum;
    __syncthreads();
    for (int o = 1; o < 256; o <<= 1) {
        int x = (t >= o) ? s[t - o] : 0;
        __syncthreads();
        s[t] += x;
        __syncthreads();
    }
    int run = bsum[blockIdx.x] + s[t] - sum;
#pragma unroll
    for (int j = 0; j < 8; ++j) {
        int i = base + j;
        if (i < N) {
            off[i] = run;
            cursor[i] = run;
            run += loc[j];
        }
    }
}

// ---------------------------------------------------------------- edge sort
__global__ __launch_bounds__(256) void sort_kernel(const int* __restrict__ src,
                                                   const int* __restrict__ dst,
                                                   const float* __restrict__ ew,
                                                   int* __restrict__ cursor,
                                                   int2* __restrict__ payload, int E) {
    int e = blockIdx.x * 256 + threadIdx.x;
    if (e < E) {
        int d = dst[e];
        int p = atomicAdd(&cursor[d], 1);
        int2 pl;
        pl.x = src[e];
        pl.y = __float_as_int(ew[e]);
        payload[p] = pl;
    }
}

// ---------------------------------------------------------------- W fragment prep
// Pack W [256][64] fp32 into bf16 MFMA B-fragments.
// grid 32 blocks (st = s*4+t), 64 threads (lane). B frag for k-step s, n-tile t:
// lane l holds W[32s + (l>>4)*8 + j][16t + (l&15)], j=0..7.
__global__ __launch_bounds__(64) void wfrag_kernel(const float* __restrict__ W,
                                                   __bf16* __restrict__ wfrag) {
    const int st = blockIdx.x;
    const int s = st >> 2, t = st & 3;
    const int l = threadIdx.x;
    const int n = t * 16 + (l & 15);
    const int k0 = s * 32 + (l >> 4) * 8;
    bf16x8 f;
#pragma unroll
    for (int j = 0; j < 8; ++j)
        f[j] = (__bf16)W[(k0 + j) * OUT_F + n];
    *(bf16x8*)(wfrag + (size_t)(st * 64 + l) * 8) = f;
}

// ---------------------------------------------------------------- MFMA GEMM
// h = feat @ W, h stored bf16. Block = 256 thr = 4 waves; wave covers 16 rows.
// A frag: lane l -> row m0+(l&15), k = s*32 + (l>>4)*8 + j (8 contiguous f32,
// loaded as 2 float4, cast to bf16). B frags from wfrag (L2-resident).
__global__ __launch_bounds__(256) void gemm_mfma_kernel(const float* __restrict__ feat,
                                                        const __bf16* __restrict__ wfrag,
                                                        __bf16* __restrict__ h, int N) {
    const int tid = threadIdx.x;
    const int wv = tid >> 6;
    const int l = tid & 63;
    const int m0 = blockIdx.x * 64 + wv * 16;
    const int q = l >> 4;
    const int row = min(m0 + (l & 15), N - 1);

    const float* __restrict__ arow = feat + (size_t)row * IN_F + q * 8;
    const bf16x8* __restrict__ wf = (const bf16x8*)wfrag; // [32 frags][64 lanes]

    f32x4 acc0 = {0.f, 0.f, 0.f, 0.f};
    f32x4 acc1 = {0.f, 0.f, 0.f, 0.f};
    f32x4 acc2 = {0.f, 0.f, 0.f, 0.f};
    f32x4 acc3 = {0.f, 0.f, 0.f, 0.f};

#pragma unroll
    for (int s = 0; s < 8; ++s) {
        float4 fa0 = *(const float4*)(arow + s * 32);
        float4 fa1 = *(const float4*)(arow + s * 32 + 4);
        bf16x8 a;
        a[0] = (__bf16)fa0.x; a[1] = (__bf16)fa0.y;
        a[2] = (__bf16)fa0.z; a[3] = (__bf16)fa0.w;
        a[4] = (__bf16)fa1.x; a[5] = (__bf16)fa1.y;
        a[6] = (__bf16)fa1.z; a[7] = (__bf16)fa1.w;
        bf16x8 b0 = wf[(s * 4 + 0) * 64 + l];
        bf16x8 b1 = wf[(s * 4 + 1) * 64 + l];
        bf16x8 b2 = wf[(s * 4 + 2) * 64 + l];
        bf16x8 b3 = wf[(s * 4 + 3) * 64 + l];
        acc0 = __builtin_amdgcn_mfma_f32_16x16x32_bf16(a, b0, acc0, 0, 0, 0);
        acc1 = __builtin_amdgcn_mfma_f32_16x16x32_bf16(a, b1, acc1, 0, 0, 0);
        acc2 = __builtin_amdgcn_mfma_f32_16x16x32_bf16(a, b2, acc2, 0, 0, 0);
        acc3 = __builtin_amdgcn_mfma_f32_16x16x32_bf16(a, b3, acc3, 0, 0, 0);
    }

    // D layout (m89-verified): col = lane&15, row = (lane>>4)*4 + reg
    const int colb = l & 15;
#pragma unroll
    for (int r = 0; r < 4; ++r) {
        int ro = m0 + q * 4 + r;
        if (ro < N) {
            __bf16* hp = h + (size_t)ro * OUT_F + colb;
            hp[0]  = (__bf16)acc0[r];
            hp[16] = (__bf16)acc1[r];
            hp[32] = (__bf16)acc2[r];
            hp[48] = (__bf16)acc3[r];
        }
    }
}

// ---------------------------------------------------------------- gather + ReLU
__global__ __launch_bounds__(256) void gather_kernel(const __bf16* __restrict__ h,
                                                     const int2* __restrict__ payload,
                                                     const int* __restrict__ off,
                                                     float* __restrict__ out, int N) {
    const int v = blockIdx.x * 4 + (threadIdx.x >> 6);
    const int lane = threadIdx.x & 63;
    if (v >= N) return;
    const int b = off[v];
    const int e = off[v + 1];
    float acc = 0.f;
    for (int i = b; i < e; ++i) {
        int2 pl = payload[i]; // broadcast across the wave
        float w = __int_as_float(pl.y);
        acc = fmaf((float)h[(size_t)pl.x * OUT_F + lane], w, acc);
    }
    out[v * OUT_F + lane] = fmaxf(acc, 0.f);
}

// ---------------------------------------------------------------- launch
extern "C" void kernel_launch(void* const* d_in, const int* in_sizes, int n_in,
                              void* d_out, int out_size, void* d_ws, size_t ws_size,
                              hipStream_t stream) {
    const float* feat = (const float*)d_in[0];
    const float* W    = (const float*)d_in[1];
    const float* ew   = (const float*)d_in[2];
    const int*   src  = (const int*)d_in[3];
    const int*   dst  = (const int*)d_in[4];
    float* out = (float*)d_out;

    const int N = in_sizes[0] / IN_F;
    const int E = in_sizes[2];

    // workspace layout (payload first to keep int2 8B-aligned)
    char* ws = (char*)d_ws;
    int2*   payload = (int2*)ws;   ws += (size_t)E * 8;           // 12.8 MB
    __bf16* h       = (__bf16*)ws; ws += (size_t)N * OUT_F * 2;   // 12.8 MB
    __bf16* wfrag   = (__bf16*)ws; ws += 32 * 64 * 8 * 2;         // 32 KB
    int*    cursor  = (int*)ws;    ws += (size_t)N * 4;           // 0.4 MB
    int*    off     = (int*)ws;    ws += (size_t)(N + 1) * 4;     // 0.4 MB
    int*    bsum    = (int*)ws;                                    // 1 KB

    hipMemsetAsync(cursor, 0, (size_t)N * 4, stream);

    const int eblocks = (E + 255) / 256;
    const int NB = (N + SCAN_ELEMS - 1) / SCAN_ELEMS;

    hipLaunchKernelGGL(hist_kernel, dim3(eblocks), dim3(256), 0, stream, dst, cursor, E);
    hipLaunchKernelGGL(scanA_kernel, dim3(NB), dim3(256), 0, stream, cursor, bsum, N);
    hipLaunchKernelGGL(scanB_kernel, dim3(1), dim3(256), 0, stream, bsum, off, NB, N);
    hipLaunchKernelGGL(scanC_kernel, dim3(NB), dim3(256), 0, stream, bsum, off, cursor, N);
    hipLaunchKernelGGL(sort_kernel, dim3(eblocks), dim3(256), 0, stream, src, dst, ew, cursor, payload, E);
    hipLaunchKernelGGL(wfrag_kernel, dim3(32), dim3(64), 0, stream, W, wfrag);
    hipLaunchKernelGGL(gemm_mfma_kernel, dim3((N + 63) / 64), dim3(256), 0, stream, feat, wfrag, h, N);
    hipLaunchKernelGGL(gather_kernel, dim3((N + 3) / 4), dim3(256), 0, stream, h, payload, off, out, N);
}

// Round 5
// 289.716 us; speedup vs baseline: 2.2945x; 1.2329x over previous
//
#include <hip/hip_runtime.h>

#define IN_F 256
#define OUT_F 64
#define SCAN_ELEMS 2048   // per block: 256 threads x 8

typedef __bf16 bf16x8 __attribute__((ext_vector_type(8)));
typedef float f32x4 __attribute__((ext_vector_type(4)));

// ---------------------------------------------------------------- histogram (4 edges/thread)
__global__ __launch_bounds__(256) void hist_kernel(const int* __restrict__ dst,
                                                   int* __restrict__ deg, int E) {
    int base = (blockIdx.x * 256 + threadIdx.x) * 4;
    if (base + 4 <= E) {
        int4 d4 = *(const int4*)(dst + base);
        atomicAdd(&deg[d4.x], 1);
        atomicAdd(&deg[d4.y], 1);
        atomicAdd(&deg[d4.z], 1);
        atomicAdd(&deg[d4.w], 1);
    } else {
        for (int e = base; e < E; ++e) atomicAdd(&deg[dst[e]], 1);
    }
}

// ---------------------------------------------------------------- scan phase A
__global__ __launch_bounds__(256) void scanA_kernel(const int* __restrict__ deg,
                                                    int* __restrict__ bsum, int N) {
    __shared__ int s[256];
    const int t = threadIdx.x;
    const int base = blockIdx.x * SCAN_ELEMS + t * 8;
    int sum = 0;
#pragma unroll
    for (int j = 0; j < 8; ++j) {
        int i = base + j;
        if (i < N) sum += deg[i];
    }
    s[t] = sum;
    __syncthreads();
    for (int o = 128; o > 0; o >>= 1) {
        if (t < o) s[t] += s[t + o];
        __syncthreads();
    }
    if (t == 0) bsum[blockIdx.x] = s[0];
}

// ---------------------------------------------------------------- scan phase B (NB <= 256)
__global__ __launch_bounds__(256) void scanB_kernel(int* __restrict__ bsum,
                                                    int* __restrict__ off, int NB, int N) {
    __shared__ int s[256];
    const int t = threadIdx.x;
    int v = (t < NB) ? bsum[t] : 0;
    s[t] = v;
    __syncthreads();
    for (int o = 1; o < 256; o <<= 1) {
        int x = (t >= o) ? s[t - o] : 0;
        __syncthreads();
        s[t] += x;
        __syncthreads();
    }
    if (t < NB) bsum[t] = s[t] - v; // exclusive block prefix
    if (t == 255) off[N] = s[255];
}

// ---------------------------------------------------------------- scan phase C
__global__ __launch_bounds__(256) void scanC_kernel(const int* __restrict__ bsum,
                                                    int* __restrict__ off,
                                                    int* __restrict__ cursor, int N) {
    __shared__ int s[256];
    const int t = threadIdx.x;
    const int base = blockIdx.x * SCAN_ELEMS + t * 8;
    int loc[8];
    int sum = 0;
#pragma unroll
    for (int j = 0; j < 8; ++j) {
        int i = base + j;
        loc[j] = (i < N) ? cursor[i] : 0;
        sum += loc[j];
    }
    s[t] = sum;
    __syncthreads();
    for (int o = 1; o < 256; o <<= 1) {
        int x = (t >= o) ? s[t - o] : 0;
        __syncthreads();
        s[t] += x;
        __syncthreads();
    }
    int run = bsum[blockIdx.x] + s[t] - sum;
#pragma unroll
    for (int j = 0; j < 8; ++j) {
        int i = base + j;
        if (i < N) {
            off[i] = run;
            cursor[i] = run;
            run += loc[j];
        }
    }
}

// ---------------------------------------------------------------- edge sort (4 edges/thread)
__global__ __launch_bounds__(256) void sort_kernel(const int* __restrict__ src,
                                                   const int* __restrict__ dst,
                                                   const float* __restrict__ ew,
                                                   int* __restrict__ cursor,
                                                   int2* __restrict__ payload, int E) {
    int base = (blockIdx.x * 256 + threadIdx.x) * 4;
    if (base + 4 <= E) {
        int4 d4 = *(const int4*)(dst + base);
        int4 s4 = *(const int4*)(src + base);
        float4 w4 = *(const float4*)(ew + base);
        int p0 = atomicAdd(&cursor[d4.x], 1);
        int p1 = atomicAdd(&cursor[d4.y], 1);
        int p2 = atomicAdd(&cursor[d4.z], 1);
        int p3 = atomicAdd(&cursor[d4.w], 1);
        payload[p0] = make_int2(s4.x, __float_as_int(w4.x));
        payload[p1] = make_int2(s4.y, __float_as_int(w4.y));
        payload[p2] = make_int2(s4.z, __float_as_int(w4.z));
        payload[p3] = make_int2(s4.w, __float_as_int(w4.w));
    } else {
        for (int e = base; e < E; ++e) {
            int p = atomicAdd(&cursor[dst[e]], 1);
            payload[p] = make_int2(src[e], __float_as_int(ew[e]));
        }
    }
}

// ---------------------------------------------------------------- W fragment prep
__global__ __launch_bounds__(64) void wfrag_kernel(const float* __restrict__ W,
                                                   __bf16* __restrict__ wfrag) {
    const int st = blockIdx.x;
    const int s = st >> 2, t = st & 3;
    const int l = threadIdx.x;
    const int n = t * 16 + (l & 15);
    const int k0 = s * 32 + (l >> 4) * 8;
    bf16x8 f;
#pragma unroll
    for (int j = 0; j < 8; ++j)
        f[j] = (__bf16)W[(k0 + j) * OUT_F + n];
    *(bf16x8*)(wfrag + (size_t)(st * 64 + l) * 8) = f;
}

// ---------------------------------------------------------------- MFMA GEMM
__global__ __launch_bounds__(256) void gemm_mfma_kernel(const float* __restrict__ feat,
                                                        const __bf16* __restrict__ wfrag,
                                                        __bf16* __restrict__ h, int N) {
    const int tid = threadIdx.x;
    const int wv = tid >> 6;
    const int l = tid & 63;
    const int m0 = blockIdx.x * 64 + wv * 16;
    const int q = l >> 4;
    const int row = min(m0 + (l & 15), N - 1);

    const float* __restrict__ arow = feat + (size_t)row * IN_F + q * 8;
    const bf16x8* __restrict__ wf = (const bf16x8*)wfrag; // [32 frags][64 lanes]

    f32x4 acc0 = {0.f, 0.f, 0.f, 0.f};
    f32x4 acc1 = {0.f, 0.f, 0.f, 0.f};
    f32x4 acc2 = {0.f, 0.f, 0.f, 0.f};
    f32x4 acc3 = {0.f, 0.f, 0.f, 0.f};

#pragma unroll
    for (int s = 0; s < 8; ++s) {
        float4 fa0 = *(const float4*)(arow + s * 32);
        float4 fa1 = *(const float4*)(arow + s * 32 + 4);
        bf16x8 a;
        a[0] = (__bf16)fa0.x; a[1] = (__bf16)fa0.y;
        a[2] = (__bf16)fa0.z; a[3] = (__bf16)fa0.w;
        a[4] = (__bf16)fa1.x; a[5] = (__bf16)fa1.y;
        a[6] = (__bf16)fa1.z; a[7] = (__bf16)fa1.w;
        bf16x8 b0 = wf[(s * 4 + 0) * 64 + l];
        bf16x8 b1 = wf[(s * 4 + 1) * 64 + l];
        bf16x8 b2 = wf[(s * 4 + 2) * 64 + l];
        bf16x8 b3 = wf[(s * 4 + 3) * 64 + l];
        acc0 = __builtin_amdgcn_mfma_f32_16x16x32_bf16(a, b0, acc0, 0, 0, 0);
        acc1 = __builtin_amdgcn_mfma_f32_16x16x32_bf16(a, b1, acc1, 0, 0, 0);
        acc2 = __builtin_amdgcn_mfma_f32_16x16x32_bf16(a, b2, acc2, 0, 0, 0);
        acc3 = __builtin_amdgcn_mfma_f32_16x16x32_bf16(a, b3, acc3, 0, 0, 0);
    }

    // D layout: col = lane&15, row = (lane>>4)*4 + reg
    const int colb = l & 15;
#pragma unroll
    for (int r = 0; r < 4; ++r) {
        int ro = m0 + q * 4 + r;
        if (ro < N) {
            __bf16* hp = h + (size_t)ro * OUT_F + colb;
            hp[0]  = (__bf16)acc0[r];
            hp[16] = (__bf16)acc1[r];
            hp[32] = (__bf16)acc2[r];
            hp[48] = (__bf16)acc3[r];
        }
    }
}

// ---------------------------------------------------------------- gather + ReLU (4-deep MLP)
__global__ __launch_bounds__(256) void gather_kernel(const __bf16* __restrict__ h,
                                                     const int2* __restrict__ payload,
                                                     const int* __restrict__ off,
                                                     float* __restrict__ out, int N) {
    const int v = blockIdx.x * 4 + (threadIdx.x >> 6);
    const int lane = threadIdx.x & 63;
    if (v >= N) return;
    int i = off[v];
    const int e = off[v + 1];
    float a0 = 0.f, a1 = 0.f, a2 = 0.f, a3 = 0.f;
    for (; i + 4 <= e; i += 4) {
        int2 p0 = payload[i + 0];
        int2 p1 = payload[i + 1];
        int2 p2 = payload[i + 2];
        int2 p3 = payload[i + 3];
        float h0 = (float)h[(size_t)p0.x * OUT_F + lane];
        float h1 = (float)h[(size_t)p1.x * OUT_F + lane];
        float h2 = (float)h[(size_t)p2.x * OUT_F + lane];
        float h3 = (float)h[(size_t)p3.x * OUT_F + lane];
        a0 = fmaf(h0, __int_as_float(p0.y), a0);
        a1 = fmaf(h1, __int_as_float(p1.y), a1);
        a2 = fmaf(h2, __int_as_float(p2.y), a2);
        a3 = fmaf(h3, __int_as_float(p3.y), a3);
    }
    for (; i < e; ++i) {
        int2 p = payload[i];
        a0 = fmaf((float)h[(size_t)p.x * OUT_F + lane], __int_as_float(p.y), a0);
    }
    out[v * OUT_F + lane] = fmaxf((a0 + a1) + (a2 + a3), 0.f);
}

// ---------------------------------------------------------------- launch
extern "C" void kernel_launch(void* const* d_in, const int* in_sizes, int n_in,
                              void* d_out, int out_size, void* d_ws, size_t ws_size,
                              hipStream_t stream) {
    const float* feat = (const float*)d_in[0];
    const float* W    = (const float*)d_in[1];
    const float* ew   = (const float*)d_in[2];
    const int*   src  = (const int*)d_in[3];
    const int*   dst  = (const int*)d_in[4];
    float* out = (float*)d_out;

    const int N = in_sizes[0] / IN_F;
    const int E = in_sizes[2];

    // workspace layout (payload first to keep int2 8B-aligned)
    char* ws = (char*)d_ws;
    int2*   payload = (int2*)ws;   ws += (size_t)E * 8;           // 12.8 MB
    __bf16* h       = (__bf16*)ws; ws += (size_t)N * OUT_F * 2;   // 12.8 MB
    __bf16* wfrag   = (__bf16*)ws; ws += 32 * 64 * 8 * 2;         // 32 KB
    int*    cursor  = (int*)ws;    ws += (size_t)N * 4;           // 0.4 MB
    int*    off     = (int*)ws;    ws += (size_t)(N + 1) * 4;     // 0.4 MB
    int*    bsum    = (int*)ws;                                    // 1 KB

    hipMemsetAsync(cursor, 0, (size_t)N * 4, stream);

    const int e4blocks = (E + 1023) / 1024; // 4 edges/thread
    const int NB = (N + SCAN_ELEMS - 1) / SCAN_ELEMS;

    hipLaunchKernelGGL(hist_kernel, dim3(e4blocks), dim3(256), 0, stream, dst, cursor, E);
    hipLaunchKernelGGL(scanA_kernel, dim3(NB), dim3(256), 0, stream, cursor, bsum, N);
    hipLaunchKernelGGL(scanB_kernel, dim3(1), dim3(256), 0, stream, bsum, off, NB, N);
    hipLaunchKernelGGL(scanC_kernel, dim3(NB), dim3(256), 0, stream, bsum, off, cursor, N);
    hipLaunchKernelGGL(sort_kernel, dim3(e4blocks), dim3(256), 0, stream, src, dst, ew, cursor, payload, E);
    hipLaunchKernelGGL(wfrag_kernel, dim3(32), dim3(64), 0, stream, W, wfrag);
    hipLaunchKernelGGL(gemm_mfma_kernel, dim3((N + 63) / 64), dim3(256), 0, stream, feat, wfrag, h, N);
    hipLaunchKernelGGL(gather_kernel, dim3((N + 3) / 4), dim3(256), 0, stream, h, payload, off, out, N);
}